// Round 9
// baseline (160.781 us; speedup 1.0000x reference)
//
#include <hip/hip_runtime.h>
#include <math.h>

#define F 256
#define TBL 2048
#define TBLK (TBL / 16)      // 128 table-builder blocks
#define GA 1172              // phase-A blocks: 4688 waves = ngroups(300000/64)
#define SMAX 8.0f
#define EPS 1e-8f

typedef float f4 __attribute__((ext_vector_type(4)));

__device__ __forceinline__ float softplus_f(float t) {
    // max(t,0) + ln2 * log2(1 + 2^(-|t|*log2e)); p<=1 so direct log2(1+p) is accurate
    float p = exp2f(-fabsf(t) * 1.44269504089f);
    return fmaxf(t, 0.f) + 0.69314718056f * log2f(1.f + p);
}

// ---------------------------------------------------------------------------
// k_prep (wide): block g<F computes u[g] = sum_f Wk[f]*Wq[f,g]; block F: c0.
// anorm zeroed across the grid.
// ---------------------------------------------------------------------------
__global__ __launch_bounds__(256)
void k_prep(const float* __restrict__ Wq, const float* __restrict__ bq,
            const float* __restrict__ Wk, float* __restrict__ u,
            float* __restrict__ c0, float* __restrict__ anorm, int B)
{
    __shared__ float red[256];
    const int t = threadIdx.x;
    const int g = blockIdx.x;

    int j = g * 256 + t;
    if (j < B) anorm[j] = 0.f;

    float p;
    if (g < F) p = Wk[t] * Wq[(size_t)t * F + g];
    else       p = Wk[t] * bq[t];
    red[t] = p;
    __syncthreads();
    #pragma unroll
    for (int s = 128; s > 0; s >>= 1) {
        if (t < s) red[t] += red[t + s];
        __syncthreads();
    }
    if (t == 0) {
        if (g < F) u[g] = red[0];
        else       *c0 = red[0];
    }
}

// ---------------------------------------------------------------------------
// phase-A round helper: 4 rows per round, 16-lane-per-row layout.
// ---------------------------------------------------------------------------
template <bool GUARD>
__device__ __forceinline__ void roundA(const float* __restrict__ x, int N,
                                       int m0, int j, int rsub, int kc,
                                       const f4* uf, int lane, float& dval)
{
    int row = m0 + (j << 2) + rsub;
    f4 v0 = {0.f, 0.f, 0.f, 0.f}, v1 = v0, v2 = v0, v3 = v0;
    if (!GUARD || row < N) {
        const float* xr = x + (size_t)row * F + (kc << 2);
        v0 = __builtin_nontemporal_load((const f4*)xr);
        v1 = __builtin_nontemporal_load((const f4*)(xr + 64));
        v2 = __builtin_nontemporal_load((const f4*)(xr + 128));
        v3 = __builtin_nontemporal_load((const f4*)(xr + 192));
    }
    float dA = v0.x * uf[0].x + v0.y * uf[0].y + v0.z * uf[0].z + v0.w * uf[0].w;
    float dB = v1.x * uf[1].x + v1.y * uf[1].y + v1.z * uf[1].z + v1.w * uf[1].w;
    float dC = v2.x * uf[2].x + v2.y * uf[2].y + v2.z * uf[2].z + v2.w * uf[2].w;
    float dD = v3.x * uf[3].x + v3.y * uf[3].y + v3.z * uf[3].z + v3.w * uf[3].w;
    float d = (dA + dB) + (dC + dD);
    // 4-level butterfly within each 16-lane group (4 rows reduced at once)
    d += __shfl_xor(d, 1);
    d += __shfl_xor(d, 2);
    d += __shfl_xor(d, 4);
    d += __shfl_xor(d, 8);
    // distribute: lane l takes row m0+l at round j == (l>>2), from lane (l&3)*16
    float got = __shfl(d, (lane & 3) << 4);
    if ((lane >> 2) == j) dval = got;
}

// ---------------------------------------------------------------------------
// k_main: blocks [0,TBLK): lookup table g(s)=s*Wv+h2(s), 16 rows/block
//         blocks [TBLK,..): phase A — 64 rows/wave-group, lane-parallel
//         softplus + segmented wave scan for anorm.
// ---------------------------------------------------------------------------
__global__ __launch_bounds__(256)
void k_main(const float* __restrict__ x, const float* __restrict__ E,
            const int* __restrict__ seg, const float* __restrict__ u,
            const float* __restrict__ c0p, const float* __restrict__ Wv,
            const float* __restrict__ W1, const float* __restrict__ b1,
            const float* __restrict__ W2, const float* __restrict__ b2,
            float* __restrict__ a_arr, float* __restrict__ anorm,
            float* __restrict__ table, int N)
{
    __shared__ float zbuf[16][F];   // table blocks only

    if ((int)blockIdx.x >= TBLK) {
        const int lane = threadIdx.x & 63;
        const int wid  = threadIdx.x >> 6;
        const int gwave = (blockIdx.x - TBLK) * 4 + wid;
        const int nwaves = GA * 4;
        const int ngroups = (N + 63) >> 6;
        const int rsub = lane >> 4;          // which of 4 rows this lane helps
        const int kc   = lane & 15;          // k-chunk within row

        f4 uf[4];
        #pragma unroll
        for (int kk = 0; kk < 4; ++kk)
            uf[kk] = *(const f4*)(u + (kc << 2) + (kk << 6));
        const float c0 = *c0p;

        for (int g = gwave; g < ngroups; g += nwaves) {
            const int m0 = g << 6;
            const int cnt = min(64, N - m0);
            float dval = 0.f;

            if (cnt == 64) {
                #pragma unroll 4
                for (int j = 0; j < 16; ++j)
                    roundA<false>(x, N, m0, j, rsub, kc, uf, lane, dval);
            } else {
                for (int j = 0; j < 16; ++j)
                    roundA<true>(x, N, m0, j, rsub, kc, uf, lane, dval);
            }

            // ----- epilogue: 64 rows lane-parallel -----
            const int rr = m0 + lane;
            const bool valid = lane < cnt;
            int b = 0;
            if (valid) b = seg[rr];
            float a = 0.f;
            if (valid) {
                float e = fabsf(E[b]);
                a = softplus_f(e * (dval + c0) * 0.0625f);
                a_arr[rr] = a;
            }

            // segmented inclusive scan of a by b
            int bprev = __shfl_up(b, 1);
            const bool isStart = (lane == 0) || (b != bprev);
            float s = a;
            int fl = isStart ? 1 : 0;
            #pragma unroll
            for (int off = 1; off < 64; off <<= 1) {
                float s2 = __shfl_up(s, off);
                int   f2 = __shfl_up(fl, off);
                if (lane >= off && !fl) { s += s2; fl |= f2; }
            }
            int nextStart = __shfl_down((int)isStart, 1);
            const bool isEnd = (lane == 63) || nextStart;
            if (valid && isEnd) atomicAdd(&anorm[b], s);
        }
    } else {
        // ----- table build -----
        const int tb = blockIdx.x;
        const int i  = threadIdx.x;
        const float delta = SMAX / (float)(TBL - 1);
        const float wv = Wv[i];

        #pragma unroll
        for (int r = 0; r < 16; ++r) {
            float s  = (float)(tb * 16 + r) * delta;
            float zv = s * wv;
            zbuf[r][i] = zv / (1.f + __expf(-zv));               // silu(y)
        }
        __syncthreads();

        float acc[16];
        float bb = b1[i];
        #pragma unroll
        for (int r = 0; r < 16; ++r) acc[r] = bb;
        const f4* w1row = (const f4*)(W1 + (size_t)i * F);
        for (int fc = 0; fc < F / 4; ++fc) {
            f4 w4 = w1row[fc];
            #pragma unroll
            for (int r = 0; r < 16; ++r) {
                f4 z4 = *(const f4*)&zbuf[r][fc * 4];
                acc[r] += w4.x * z4.x + w4.y * z4.y + w4.z * z4.z + w4.w * z4.w;
            }
        }
        __syncthreads();
        #pragma unroll
        for (int r = 0; r < 16; ++r)
            zbuf[r][i] = acc[r] / (1.f + __expf(-acc[r]));       // silu(h1)
        __syncthreads();

        bb = b2[i];
        #pragma unroll
        for (int r = 0; r < 16; ++r) acc[r] = bb;
        const f4* w2row = (const f4*)(W2 + (size_t)i * F);
        for (int fc = 0; fc < F / 4; ++fc) {
            f4 w4 = w2row[fc];
            #pragma unroll
            for (int r = 0; r < 16; ++r) {
                f4 z4 = *(const f4*)&zbuf[r][fc * 4];
                acc[r] += w4.x * z4.x + w4.y * z4.y + w4.z * z4.z + w4.w * z4.w;
            }
        }
        #pragma unroll
        for (int r = 0; r < 16; ++r) {
            float s = (float)(tb * 16 + r) * delta;
            table[(size_t)(tb * 16 + r) * F + i] = s * wv + acc[r];
        }
    }
}

// ---------------------------------------------------------------------------
// k_out: one 64-row group per wave; lane-parallel index precompute, then a
// fully unrolled gather/store loop with readlane (SGPR table bases).
// ---------------------------------------------------------------------------
__global__ __launch_bounds__(256)
void k_out(const float* __restrict__ a_arr, const int* __restrict__ seg,
           const float* __restrict__ E, const float* __restrict__ anorm,
           const float* __restrict__ table, float* __restrict__ out, int N)
{
    const int lane = threadIdx.x & 63;
    const int wid  = threadIdx.x >> 6;
    const int g0   = blockIdx.x * 4 + wid;
    const int nwaves = gridDim.x * 4;
    const int ngroups = (N + 63) >> 6;
    const float inv_delta = (float)(TBL - 1) / SMAX;

    for (int g = g0; g < ngroups; g += nwaves) {
        const int m0 = g << 6;
        const int cnt = min(64, N - m0);

        int idx = 0;
        if (lane < cnt) {
            int r = m0 + lane;
            int b = seg[r];                       // coalesced
            float a = a_arr[r];                   // coalesced
            float s = a / (anorm[b] + EPS) * fabsf(E[b]);
            int i0 = (int)(s * inv_delta + 0.5f);
            idx = min(max(i0, 0), TBL - 1) * F;
        }

        if (cnt == 64) {
            #pragma unroll
            for (int r = 0; r < 64; r += 4) {
                int i0 = __builtin_amdgcn_readlane(idx, r);
                int i1 = __builtin_amdgcn_readlane(idx, r + 1);
                int i2 = __builtin_amdgcn_readlane(idx, r + 2);
                int i3 = __builtin_amdgcn_readlane(idx, r + 3);
                f4 t0 = *((const f4*)(table + i0) + lane);
                f4 t1 = *((const f4*)(table + i1) + lane);
                f4 t2 = *((const f4*)(table + i2) + lane);
                f4 t3 = *((const f4*)(table + i3) + lane);
                __builtin_nontemporal_store(t0, (f4*)(out + (size_t)(m0 + r)     * F) + lane);
                __builtin_nontemporal_store(t1, (f4*)(out + (size_t)(m0 + r + 1) * F) + lane);
                __builtin_nontemporal_store(t2, (f4*)(out + (size_t)(m0 + r + 2) * F) + lane);
                __builtin_nontemporal_store(t3, (f4*)(out + (size_t)(m0 + r + 3) * F) + lane);
            }
        } else {
            for (int r = 0; r < cnt; ++r) {
                int i0 = __shfl(idx, r);
                f4 t0 = *((const f4*)(table + i0) + lane);
                __builtin_nontemporal_store(t0, (f4*)(out + (size_t)(m0 + r) * F) + lane);
            }
        }
    }
}

// ---------------------------------------------------------------------------
extern "C" void kernel_launch(void* const* d_in, const int* in_sizes, int n_in,
                              void* d_out, int out_size, void* d_ws, size_t ws_size,
                              hipStream_t stream)
{
    const float* x   = (const float*)d_in[0];
    const float* E   = (const float*)d_in[1];
    const int*   seg = (const int*)  d_in[2];
    const float* Wq  = (const float*)d_in[4];
    const float* bq  = (const float*)d_in[5];
    const float* Wk  = (const float*)d_in[6];
    const float* Wv  = (const float*)d_in[7];
    const float* W1  = (const float*)d_in[8];
    const float* b1  = (const float*)d_in[9];
    const float* W2  = (const float*)d_in[10];
    const float* b2  = (const float*)d_in[11];

    const int N = in_sizes[0] / F;
    const int B = in_sizes[1];
    float* out = (float*)d_out;

    float* ws    = (float*)d_ws;
    float* table = ws;                          // TBL*F floats (2 MB)
    float* u     = table + (size_t)TBL * F;     // F
    float* c0    = u + F;                       // 1 (padded to 4)
    float* anorm = c0 + 4;                      // B
    float* a_arr = anorm + B;                   // N

    k_prep<<<F + 1, 256, 0, stream>>>(Wq, bq, Wk, u, c0, anorm, B);

    k_main<<<TBLK + GA, 256, 0, stream>>>(x, E, seg, u, c0, Wv, W1, b1, W2,
                                          b2, a_arr, anorm, table, N);

    k_out<<<1172, 256, 0, stream>>>(a_arr, seg, E, anorm, table, out, N);
}